// Round 15
// baseline (53.059 us; speedup 1.0000x reference)
//
#include <hip/hip_runtime.h>
#include <hip/hip_bf16.h>

constexpr int B   = 8;
constexpr int N   = 1024;
constexpr int DIN = 128;
constexpr int H   = 8;
constexpr int D   = 16;
constexpr int HD  = 128;   // H*D
constexpr int TI  = 16;    // i-rows per k_attn block (MFMA M)

#define LOG2E 1.4426950408889634f
#define TCLAMP 30.0f       // never binds on real data (|s·log2e| < ~5)

typedef __attribute__((ext_vector_type(8))) short bf16x8;  // MFMA A/B frag
typedef __attribute__((ext_vector_type(4))) float f32x4;   // MFMA C/D frag

__device__ inline float fast_exp2(float x) {
#if __has_builtin(__builtin_amdgcn_exp2f)
    return __builtin_amdgcn_exp2f(x);
#else
    return exp2f(x);
#endif
}

// ---------------------------------------------------------------------------
// Pack adj -> bitmask bm[row][32] u32. One row per wave: 16 independent
// coalesced 256B loads (deep ILP), 32 contiguous mask words stored per row.
// ---------------------------------------------------------------------------
__global__ __launch_bounds__(256) void k_pack(const int* __restrict__ adj,
                                              unsigned int* __restrict__ bm)
{
    const int lane = threadIdx.x & 63;
    const size_t row = (size_t)blockIdx.x * 4 + (threadIdx.x >> 6);
    const int* ar = adj + row * N + lane;
    unsigned int* dst = bm + row * 32;
    #pragma unroll
    for (int tt = 0; tt < 16; ++tt) {
        const unsigned long long m = __ballot(ar[tt * 64] != 0);
        if (lane == 0)  dst[2 * tt]     = (unsigned int)m;
        if (lane == 32) dst[2 * tt + 1] = (unsigned int)(m >> 32);
    }
}

// ---------------------------------------------------------------------------
// Kernel 1: MFMA projection. Block = 16 rows, grid 512 (2 blocks/CU), 256 thr.
//   Wh = h @ W (bf16 MFMA, f32 acc) -> WhT bf16 [b][c][n]
//   tI/tJ[b][h][n] = (Wh . a_src/dst) * log2e, clamped
// ---------------------------------------------------------------------------
__global__ __launch_bounds__(256) void k_proj(
    const float* __restrict__ hsrc,
    const float* __restrict__ W,
    const float* __restrict__ a,
    __hip_bfloat16* __restrict__ WhT,  // [B][HD][N]
    float* __restrict__ tI,            // [B][H][N]
    float* __restrict__ tJ)            // [B][H][N]
{
    const int row0 = blockIdx.x * 16;    // global row (b*N+n)
    const int b    = row0 >> 10;
    const int n0   = row0 & (N - 1);
    const int t    = threadIdx.x;
    const int lane = t & 63, wave = t >> 6;
    const int mn   = lane & 15, kg = lane >> 4;

    __shared__ __align__(16) __hip_bfloat16 hA[16][136];   // [row][k]
    __shared__ __align__(16) __hip_bfloat16 Wt[128][136];  // [col][k]

    // stage h-tile (16x128 f32 -> bf16)
    {
        const float4* hf = reinterpret_cast<const float4*>(hsrc + (size_t)row0 * DIN);
        #pragma unroll
        for (int u = 0; u < 2; ++u) {
            const int idx = t + u * 256;          // float4 index
            const float4 v = hf[idx];
            const int r = idx >> 5, c4 = (idx & 31) * 4;
            hA[r][c4]     = __float2bfloat16(v.x);
            hA[r][c4 + 1] = __float2bfloat16(v.y);
            hA[r][c4 + 2] = __float2bfloat16(v.z);
            hA[r][c4 + 3] = __float2bfloat16(v.w);
        }
    }
    // stage W transposed (128x128 f32 [k][c] -> bf16 [c][k])
    {
        const float4* wf = reinterpret_cast<const float4*>(W);
        #pragma unroll
        for (int u = 0; u < 16; ++u) {
            const int idx = t + u * 256;
            const float4 v = wf[idx];
            const int k = idx >> 5, c0 = (idx & 31) * 4;
            Wt[c0][k]     = __float2bfloat16(v.x);
            Wt[c0 + 1][k] = __float2bfloat16(v.y);
            Wt[c0 + 2][k] = __float2bfloat16(v.z);
            Wt[c0 + 3][k] = __float2bfloat16(v.w);
        }
    }
    __syncthreads();

    f32x4 acc[2];
    acc[0] = (f32x4){0.f, 0.f, 0.f, 0.f};
    acc[1] = (f32x4){0.f, 0.f, 0.f, 0.f};

    #pragma unroll
    for (int kk = 0; kk < 4; ++kk) {
        const bf16x8 af = *reinterpret_cast<const bf16x8*>(
            &hA[mn][kk * 32 + kg * 8]);
        #pragma unroll
        for (int f = 0; f < 2; ++f) {
            const int F = wave * 2 + f;           // col-frag = head
            const bf16x8 bfr = *reinterpret_cast<const bf16x8*>(
                &Wt[F * 16 + mn][kk * 32 + kg * 8]);
            acc[f] = __builtin_amdgcn_mfma_f32_16x16x32_bf16(af, bfr, acc[f], 0, 0, 0);
        }
    }

    // epilogue: WhT store + tI/tJ shuffle-reduce (head = F, d = mn)
    #pragma unroll
    for (int f = 0; f < 2; ++f) {
        const int F = wave * 2 + f;
        const float as = a[F * 32 + mn];       // a[h][d]
        const float ad = a[F * 32 + 16 + mn];  // a[h][D+d]
        #pragma unroll
        for (int r = 0; r < 4; ++r) {
            const int n = n0 + kg * 4 + r;
            WhT[((size_t)(b * HD + F * 16 + mn)) * N + n] =
                __float2bfloat16(acc[f][r]);
            float vi = acc[f][r] * as;
            float vj = acc[f][r] * ad;
            #pragma unroll
            for (int m = 1; m < 16; m <<= 1) {
                vi += __shfl_xor(vi, m);
                vj += __shfl_xor(vj, m);
            }
            if (mn == 0) {
                tI[((size_t)(b * H + F)) * N + n] = fminf(vi * LOG2E, TCLAMP);
                tJ[((size_t)(b * H + F)) * N + n] = fminf(vj * LOG2E, TCLAMP);
            }
        }
    }
}

// ---------------------------------------------------------------------------
// Kernel 2: fused attention — TLP version. Block = 128 thr = 2 waves = the
// two j-halves of one (i-tile, b, head); grid (64, 8, 8) = 8192 waves = 100%
// of chip wave capacity at VGPR<=64 (8 waves/SIMD). No software pipelining —
// wave-level parallelism hides the per-step load latency.
// Lane (mn,kg) owns row i0+mn; A-frag scores built in registers
// (k = s*32+kg*8+e), matching the MFMA A layout.
// accO += P x WhT, accD += P x 1; epilogue reduces the two j-halves via LDS;
// out = accO/accD (softmax shift-invariant; scores clamped in k_proj).
// ---------------------------------------------------------------------------
__global__ __launch_bounds__(128, 8) void k_attn(
    const unsigned int*   __restrict__ bm,     // [B*N][32] u32
    const __hip_bfloat16* __restrict__ WhT,    // [B][HD][N]
    const float*          __restrict__ tI,     // [B][H][N]
    const float*          __restrict__ tJ,     // [B][H][N]
    float*                __restrict__ out)    // [B][N][HD]
{
    const int b    = blockIdx.y;
    const int i0   = blockIdx.x * TI;
    const int h    = blockIdx.z;               // head
    const int wv   = threadIdx.x >> 6;         // j-half
    const int lane = threadIdx.x & 63;
    const int mn   = lane & 15, kg = lane >> 4;
    const int row  = i0 + mn;

    const float Arow = tI[((size_t)(b * H + h)) * N + row];
    const float* tjrow = tJ + ((size_t)(b * H + h)) * N + wv * 512 + kg * 8;
    const __hip_bfloat16* wrow =
        WhT + ((size_t)(b * HD + h * 16 + mn)) * N + wv * 512 + kg * 8;
    const unsigned int* mrow =
        bm + ((size_t)(b * N) + row) * 32 + wv * 16;

    f32x4 accO = {0.f, 0.f, 0.f, 0.f};
    f32x4 accD = {0.f, 0.f, 0.f, 0.f};
    bf16x8 ones;
    #pragma unroll
    for (int e = 0; e < 8; ++e) ones[e] = (short)0x3F80;   // bf16 1.0

    #pragma unroll 4
    for (int s = 0; s < 16; ++s) {             // 32 j's per step, 512 total
        const unsigned int m8 = (mrow[s] >> (kg * 8)) & 0xFFu;
        const float4 t0 = *reinterpret_cast<const float4*>(tjrow + s * 32);
        const float4 t1 = *reinterpret_cast<const float4*>(tjrow + s * 32 + 4);
        const bf16x8 wfr = *reinterpret_cast<const bf16x8*>(wrow + s * 32);

        const float tv[8] = {t0.x, t0.y, t0.z, t0.w, t1.x, t1.y, t1.z, t1.w};
        bf16x8 af;
        #pragma unroll
        for (int e = 0; e < 8; ++e) {
            const float x = Arow + tv[e];
            float sc = fmaxf(x, 0.2f * x);
            sc = ((m8 >> e) & 1u) ? sc : -1.0e30f;
            af[e] = (short)__bfloat16_as_ushort(
                __float2bfloat16(fast_exp2(sc)));
        }
        accO = __builtin_amdgcn_mfma_f32_16x16x32_bf16(af, wfr, accO, 0, 0, 0);
        accD = __builtin_amdgcn_mfma_f32_16x16x32_bf16(af, ones, accD, 0, 0, 0);
    }

    // ---- combine j-halves (LDS) + normalize + store ----
    __shared__ float redO[64][4];
    __shared__ float redD[64][4];
    if (wv == 1) {
        #pragma unroll
        for (int r = 0; r < 4; ++r) {
            redO[lane][r] = accO[r];
            redD[lane][r] = accD[r];
        }
    }
    __syncthreads();
    if (wv == 0) {
        #pragma unroll
        for (int r = 0; r < 4; ++r) {
            const float o = accO[r] + redO[lane][r];
            const float d = accD[r] + redD[lane][r];
            out[((size_t)(b * N) + i0 + kg * 4 + r) * HD + h * 16 + mn] = o / d;
        }
    }
}

// ---------------------------------------------------------------------------
extern "C" void kernel_launch(void* const* d_in, const int* in_sizes, int n_in,
                              void* d_out, int out_size, void* d_ws, size_t ws_size,
                              hipStream_t stream)
{
    const float* h   = (const float*)d_in[0];   // f32 (proven R3/R5)
    const int*   adj = (const int*)d_in[1];
    const float* W   = (const float*)d_in[2];
    const float* a   = (const float*)d_in[3];
    float* out = (float*)d_out;

    float* ws = (float*)d_ws;
    float* tI = ws;                              // B*H*N f32 (256 KB)
    float* tJ = ws + (size_t)B * H * N;          // B*H*N f32 (256 KB)
    __hip_bfloat16* WhT = (__hip_bfloat16*)(ws + (size_t)2 * B * H * N); // 2 MB
    unsigned int* bm = (unsigned int*)((char*)WhT +
                       (size_t)B * N * HD * sizeof(__hip_bfloat16));     // 1 MB

    k_pack<<<dim3(B * N / 4), dim3(256), 0, stream>>>(adj, bm);
    k_proj<<<dim3(B * N / 16), dim3(256), 0, stream>>>(h, W, a, WhT, tI, tJ);
    k_attn<<<dim3(N / TI, B, H), dim3(128), 0, stream>>>(bm, WhT, tI, tJ, out);
}